// Round 7
// baseline (598.843 us; speedup 1.0000x reference)
//
#include <hip/hip_runtime.h>
#include <hip/hip_bf16.h>

// B=32, C=32, H=W=256, regions 4x4 of 64x64.
// Round 7: stats kernel + persistent per-(b,p) conv kernel with 16-row-slot
// LDS ring buffer (64KB, 2 blocks/CU) and split-stage software pipeline:
// loads for rows t+1 are in flight during MFMA of tile t (T14 pattern).

#define EPS 1e-5f

typedef float f32x4 __attribute__((ext_vector_type(4)));
typedef __bf16 bf16x8 __attribute__((ext_vector_type(8)));
typedef short short8 __attribute__((ext_vector_type(8)));

__device__ inline short f2bf(float f) {
  union { __hip_bfloat16 h; short s; } u;
  u.h = __float2bfloat16(f);
  return u.s;
}

// ---------------- Kernel 1: per-(b,c) plane stats, contiguous sweep ----------
__global__ __launch_bounds__(256) void stats_partial(
    const float* __restrict__ x, float* __restrict__ ws_sum,
    float* __restrict__ ws_sq) {
  int plane = blockIdx.x;            // b*32 + c
  const float* base = x + (size_t)plane * 65536;
  int t = threadIdx.x;
  float s[4] = {0.f, 0.f, 0.f, 0.f}, q[4] = {0.f, 0.f, 0.f, 0.f};
#pragma unroll
  for (int R = 0; R < 4; ++R) {
#pragma unroll
    for (int ii = 0; ii < 16; ++ii) {
      int idx4 = (R * 16 + ii) * 256 + t;     // float4 index
      float4 v = *reinterpret_cast<const float4*>(base + (size_t)idx4 * 4);
      s[R] += (v.x + v.y) + (v.z + v.w);
      q[R] += (v.x * v.x + v.y * v.y) + (v.z * v.z + v.w * v.w);
    }
  }
#pragma unroll
  for (int R = 0; R < 4; ++R) {
#pragma unroll
    for (int off = 8; off; off >>= 1) {
      s[R] += __shfl_down(s[R], off);
      q[R] += __shfl_down(q[R], off);
    }
  }
  __shared__ float red[2][4][4][4];  // [s|q][wave][Cc][R]
  int lane = t & 63, wv = t >> 6;
  if ((lane & 15) == 0) {
    int Cc = lane >> 4;
#pragma unroll
    for (int R = 0; R < 4; ++R) {
      red[0][wv][Cc][R] = s[R];
      red[1][wv][Cc][R] = q[R];
    }
  }
  __syncthreads();
  if (t < 16) {                      // t == p
    int R = t >> 2, Cc = t & 3;
    float S = 0.f, Q = 0.f;
#pragma unroll
    for (int w = 0; w < 4; ++w) {
      S += red[0][w][Cc][R];
      Q += red[1][w][Cc][R];
    }
    ws_sum[plane * 16 + t] = S;
    ws_sq[plane * 16 + t] = Q;
  }
}

// ---------------- Kernel 2: pack conv_w into MFMA A-fragments ----------------
__global__ __launch_bounds__(256) void weights_prep(
    const float* __restrict__ conv_w, unsigned short* __restrict__ wfrag) {
  int idx = blockIdx.x * 256 + threadIdx.x;
  if (idx >= 18 * 64) return;
  int lane = idx & 63;
  int th = idx >> 6;                 // t*2 + h
  int t = th >> 1, h = th & 1;
  int dy = t / 3, dx = t - dy * 3;
  int oc = h * 16 + (lane & 15);
  int ic0 = (lane >> 4) * 8;
#pragma unroll
  for (int j = 0; j < 8; ++j) {
    float w = conv_w[((oc * 32 + ic0 + j) * 3 + dy) * 3 + dx];
    wfrag[(size_t)idx * 8 + j] = (unsigned short)f2bf(w);
  }
}

// ---------------- Kernel 3: persistent per-(b,p) finalize + pipelined conv ---
// 512 blocks x 512 threads. LDS ring: 16 row-slots x 64 cols x 32 ch bf16
// = 65536 B -> 2 blocks/CU. slot(lr) = (lr+16)&15.
// Per 8-row tile: [issue 6-row loads] compute rows 0..3 [write] barrier
//                 [issue 2-row loads] compute rows 4..7 [write] barrier.
__global__ __launch_bounds__(512, 4) void conv_pipe(
    const float* __restrict__ x, const unsigned short* __restrict__ wfrag,
    const float* __restrict__ conv_b, const float* __restrict__ prelu_a,
    const float* __restrict__ ws_sum, const float* __restrict__ ws_sq,
    const float* __restrict__ gamma, const float* __restrict__ beta,
    float* __restrict__ out) {
  __shared__ short ring[16 * 64 * 32];   // 65536 B

  int blk = blockIdx.x;              // b*16 + p
  int b = blk >> 4, p = blk & 15;
  int R = p >> 2, Cc = p & 3;
  int tid = threadIdx.x;
  int lane = tid & 63;

  // ---- local finalize: per-channel scale/shift for region p
  float* abuf = (float*)ring;        // [0..31]=a, [32..63]=b (reused after)
  if (tid < 32) {
    int c = tid;
    float S = 0.f, Q = 0.f;
#pragma unroll
    for (int bb = 0; bb < 32; ++bb) {
      int idx = (bb * 32 + c) * 16 + p;
      S += ws_sum[idx];
      Q += ws_sq[idx];
    }
    const float inv = 1.0f / 131072.0f;
    float mean = S * inv;
    float var = Q * inv - mean * mean;
    float rstd = rsqrtf(var + EPS);
    float a = rstd * gamma[c];
    abuf[c] = a;
    abuf[32 + c] = beta[c] - mean * a;
  }
  __syncthreads();

  // staging decomposition: fixed per thread
  int s = (tid >> 4) & 3;            // ic-slice (8 ch)
  int c4 = tid & 15;                 // col-quad
  int ic0 = s * 8;
  float a_r[8], b_r[8];
#pragma unroll
  for (int j = 0; j < 8; ++j) {
    a_r[j] = abuf[ic0 + j];
    b_r[j] = abuf[32 + ic0 + j];
  }
  float pa = prelu_a[0];
  __syncthreads();                   // abuf consumed; ring free for staging

  int l15 = lane & 15, l4 = lane >> 4;
  int wv = tid >> 6;                 // 0..7
  f32x4 bias0, bias1;
#pragma unroll
  for (int i = 0; i < 4; ++i) {
    bias0[i] = conv_b[l4 * 4 + i];
    bias1[i] = conv_b[16 + l4 * 4 + i];
  }
  const short8 z8 = {0, 0, 0, 0, 0, 0, 0, 0};

  // ---- staging helpers (load split from write for pipelining)
  auto stage_load = [&](f32x4(&vv)[8], int lr) {
#pragma unroll
    for (int kk = 0; kk < 8; ++kk) vv[kk] = f32x4{0.f, 0.f, 0.f, 0.f};
    if ((unsigned)lr < 64u) {
      const float* xp =
          x + (((size_t)(b * 32 + ic0) * 256 + R * 64 + lr) * 256) + Cc * 64 +
          c4 * 4;
#pragma unroll
      for (int kk = 0; kk < 8; ++kk)
        vv[kk] = *reinterpret_cast<const f32x4*>(xp + (size_t)kk * 65536);
    }
  };
  auto stage_write = [&](const f32x4(&vv)[8], int lr) {
    int srl = (lr + 16) & 15;
#pragma unroll
    for (int j = 0; j < 4; ++j) {
      short8 pk;
#pragma unroll
      for (int kk = 0; kk < 8; ++kk) {
        float e = fmaf(a_r[kk], vv[kk][j], b_r[kk]);
        e = e > 0.f ? e : pa * e;
        pk[kk] = f2bf(e);
      }
      int col = c4 * 4 + j;
      int slot = (s + (col >> 1)) & 3;
      *reinterpret_cast<short8*>(&ring[(srl * 64 + col) * 32 + slot * 8]) = pk;
    }
  };
  // ---- compute one 4-row half of a tile (2 groups per wave)
  auto compute_half = [&](int h0, int hh) {
#pragma unroll
    for (int g = 0; g < 2; ++g) {
      int r = hh * 4 + (wv >> 1);
      int c0 = ((wv & 1) * 2 + g) * 16;
      f32x4 acc0 = bias0, acc1 = bias1;
#pragma unroll
      for (int t9 = 0; t9 < 9; ++t9) {
        const int dy = t9 / 3, dx = t9 - dy * 3;
        int lrr = h0 + r + dy - 1;
        int srl = (lrr + 16) & 15;
        int col_in = c0 + l15 + dx - 1;
        int colc = col_in & 63;
        int slot = (l4 + (colc >> 1)) & 3;
        short8 sv = *reinterpret_cast<const short8*>(
            &ring[(srl * 64 + colc) * 32 + slot * 8]);
        if (dx == 0 && c0 == 0 && l15 == 0) sv = z8;    // col -1 zero pad
        if (dx == 2 && c0 == 48 && l15 == 15) sv = z8;  // col 64 zero pad
        bf16x8 bv = __builtin_bit_cast(bf16x8, sv);
        short8 w0 = *reinterpret_cast<const short8*>(
            wfrag + ((size_t)(t9 * 2) * 64 + lane) * 8);
        short8 w1 = *reinterpret_cast<const short8*>(
            wfrag + ((size_t)(t9 * 2 + 1) * 64 + lane) * 8);
        acc0 = __builtin_amdgcn_mfma_f32_16x16x32_bf16(
            __builtin_bit_cast(bf16x8, w0), bv, acc0, 0, 0, 0);
        acc1 = __builtin_amdgcn_mfma_f32_16x16x32_bf16(
            __builtin_bit_cast(bf16x8, w1), bv, acc1, 0, 0, 0);
      }
      int grow = R * 64 + h0 + r;
      int gcol = Cc * 64 + c0 + l15;
      float* ob = out + (size_t)b * 2097152 + (size_t)grow * 256 + gcol;
#pragma unroll
      for (int i = 0; i < 4; ++i) {
        ob[(size_t)(l4 * 4 + i) * 65536] = acc0[i];
        ob[(size_t)(16 + l4 * 4 + i) * 65536] = acc1[i];
      }
    }
  };

  // ---- prologue: stage rows -1..8 (slots 15, 0..8)
  {
    f32x4 v[8];
    int lr = (tid >> 6) - 1;         // -1..6
    stage_load(v, lr);
    stage_write(v, lr);
    if (tid < 128) {
      int lr2 = 7 + (tid >> 6);      // 7..8
      stage_load(v, lr2);
      stage_write(v, lr2);
    }
  }
  __syncthreads();

  // ---- main loop: 8 tiles of 8 output rows
  for (int rt = 0; rt < 8; ++rt) {
    int h0 = rt * 8;

    f32x4 va[8];
    bool doA = (rt < 7) && (tid < 384);
    int lrA = h0 + 9 + (tid >> 6);   // 6 rows: h0+9..h0+14 (always <=62)
    if (doA) stage_load(va, lrA);    // loads in flight during compute
    compute_half(h0, 0);             // rows h0..h0+3
    if (doA) stage_write(va, lrA);
    __syncthreads();

    f32x4 vb[8];
    bool doB = (rt < 7) && (tid < 128);
    int lrB = h0 + 15 + (tid >> 6);  // 2 rows: h0+15,h0+16 (>=64 -> zeros)
    if (doB) stage_load(vb, lrB);
    compute_half(h0, 1);             // rows h0+4..h0+7
    if (doB) stage_write(vb, lrB);
    __syncthreads();
  }
}

extern "C" void kernel_launch(void* const* d_in, const int* in_sizes, int n_in,
                              void* d_out, int out_size, void* d_ws,
                              size_t ws_size, hipStream_t stream) {
  const float* x = (const float*)d_in[0];
  const float* gamma = (const float*)d_in[1];
  const float* beta = (const float*)d_in[2];
  const float* prelu_a = (const float*)d_in[3];
  const float* conv_w = (const float*)d_in[4];
  const float* conv_b = (const float*)d_in[5];
  float* out = (float*)d_out;

  float* ws = (float*)d_ws;
  float* ws_sum = ws;                          // 16384 floats
  float* ws_sq = ws + 16384;                   // 16384
  unsigned short* wfrag = (unsigned short*)(ws + 32768);   // 18*64*8 shorts

  weights_prep<<<5, 256, 0, stream>>>(conv_w, wfrag);
  stats_partial<<<1024, 256, 0, stream>>>(x, ws_sum, ws_sq);
  conv_pipe<<<512, 512, 0, stream>>>(x, wfrag, conv_b, prelu_a, ws_sum, ws_sq,
                                     gamma, beta, out);
}

// Round 8
// 190.111 us; speedup vs baseline: 3.1500x; 3.1500x over previous
//
#include <hip/hip_runtime.h>
#include <hip/hip_bf16.h>

// B=32, C=32, H=W=256, regions 4x4 of 64x64.
// Round 8: r5 structure + 3-deep register-pipelined staging (16 loads in
// flight before first LDS write) + finalize folded into conv. No forced
// VGPR caps (r7 lesson: launch_bounds min + big reg arrays => spills).

#define EPS 1e-5f

typedef float f32x4 __attribute__((ext_vector_type(4)));
typedef __bf16 bf16x8 __attribute__((ext_vector_type(8)));
typedef short short8 __attribute__((ext_vector_type(8)));

__device__ inline short f2bf(float f) {
  union { __hip_bfloat16 h; short s; } u;
  u.h = __float2bfloat16(f);
  return u.s;
}

// ---------------- Kernel 1: per-(b,c) plane stats, contiguous sweep ----------
__global__ __launch_bounds__(256) void stats_partial(
    const float* __restrict__ x, float* __restrict__ ws_sum,
    float* __restrict__ ws_sq) {
  int plane = blockIdx.x;            // b*32 + c
  const float* base = x + (size_t)plane * 65536;
  int t = threadIdx.x;
  float s[4] = {0.f, 0.f, 0.f, 0.f}, q[4] = {0.f, 0.f, 0.f, 0.f};
#pragma unroll
  for (int R = 0; R < 4; ++R) {
#pragma unroll
    for (int ii = 0; ii < 16; ++ii) {
      int idx4 = (R * 16 + ii) * 256 + t;     // float4 index
      float4 v = *reinterpret_cast<const float4*>(base + (size_t)idx4 * 4);
      s[R] += (v.x + v.y) + (v.z + v.w);
      q[R] += (v.x * v.x + v.y * v.y) + (v.z * v.z + v.w * v.w);
    }
  }
#pragma unroll
  for (int R = 0; R < 4; ++R) {
#pragma unroll
    for (int off = 8; off; off >>= 1) {
      s[R] += __shfl_down(s[R], off);
      q[R] += __shfl_down(q[R], off);
    }
  }
  __shared__ float red[2][4][4][4];  // [s|q][wave][Cc][R]
  int lane = t & 63, wv = t >> 6;
  if ((lane & 15) == 0) {
    int Cc = lane >> 4;
#pragma unroll
    for (int R = 0; R < 4; ++R) {
      red[0][wv][Cc][R] = s[R];
      red[1][wv][Cc][R] = q[R];
    }
  }
  __syncthreads();
  if (t < 16) {                      // t == p
    int R = t >> 2, Cc = t & 3;
    float S = 0.f, Q = 0.f;
#pragma unroll
    for (int w = 0; w < 4; ++w) {
      S += red[0][w][Cc][R];
      Q += red[1][w][Cc][R];
    }
    ws_sum[plane * 16 + t] = S;
    ws_sq[plane * 16 + t] = Q;
  }
}

// ---------------- Kernel 2: pack conv_w into MFMA A-fragments ----------------
__global__ __launch_bounds__(256) void weights_prep(
    const float* __restrict__ conv_w, unsigned short* __restrict__ wfrag) {
  int idx = blockIdx.x * 256 + threadIdx.x;
  if (idx >= 18 * 64) return;
  int lane = idx & 63;
  int th = idx >> 6;                 // t*2 + h
  int t = th >> 1, h = th & 1;
  int dy = t / 3, dx = t - dy * 3;
  int oc = h * 16 + (lane & 15);
  int ic0 = (lane >> 4) * 8;
#pragma unroll
  for (int j = 0; j < 8; ++j) {
    float w = conv_w[((oc * 32 + ic0 + j) * 3 + dy) * 3 + dx];
    wfrag[(size_t)idx * 8 + j] = (unsigned short)f2bf(w);
  }
}

// ---------------- Kernel 3: finalize + normalize+prelu -> LDS -> MFMA -------
// block = (b, p, rt): 8 output rows x 64 cols of one region. 4 waves.
// LDS: [10 rows][64 cols][4 slots x 8 ic] bf16, slot swizzled by (col>>1)&3.
__global__ __launch_bounds__(256) void conv_mfma(
    const float* __restrict__ x, const unsigned short* __restrict__ wfrag,
    const float* __restrict__ conv_b, const float* __restrict__ prelu_a,
    const float* __restrict__ ws_sum, const float* __restrict__ ws_sq,
    const float* __restrict__ gamma, const float* __restrict__ beta,
    float* __restrict__ out) {
  __shared__ short lds_y[10 * 64 * 32];  // 40960 B -> 4 blocks/CU

  int blk0 = blockIdx.x;             // 4096 blocks; chunked XCD swizzle
  int blk = (blk0 & 7) * 512 + (blk0 >> 3);
  int rt = blk & 7;
  int p = (blk >> 3) & 15;
  int b = blk >> 7;
  int R = p >> 2, Cc = p & 3;
  int h0 = rt * 8;
  int tid = threadIdx.x;
  int lane = tid & 63;
  float pa = prelu_a[0];

  // ---- local finalize: per-channel scale/shift for region p (32 threads)
  float* abuf = (float*)lds_y;       // [0..31]=a, [32..63]=b; freed below
  if (tid < 32) {
    int c = tid;
    float S = 0.f, Q = 0.f;
#pragma unroll
    for (int bb = 0; bb < 32; ++bb) {
      int idx = (bb * 32 + c) * 16 + p;
      S += ws_sum[idx];
      Q += ws_sq[idx];
    }
    const float inv = 1.0f / 131072.0f;
    float mean = S * inv;
    float var = Q * inv - mean * mean;
    float rstd = rsqrtf(var + EPS);
    float a = rstd * gamma[c];
    abuf[c] = a;
    abuf[32 + c] = beta[c] - mean * a;
  }
  __syncthreads();

  // per-thread-fixed staging decomposition
  int s = (tid >> 4) & 3;            // ic-slice
  int c4 = tid & 15;                 // col-quad
  int srb = tid >> 6;                // base staged-row
  int ic0 = s * 8;

  float a_r[8], b_r[8];
#pragma unroll
  for (int j = 0; j < 8; ++j) {
    a_r[j] = abuf[ic0 + j];
    b_r[j] = abuf[32 + ic0 + j];
  }
  __syncthreads();                   // abuf consumed; LDS free for staging

  // ---- staging helpers
  auto stage_load = [&](f32x4(&vv)[8], int sr) {
    int lr = h0 - 1 + sr;
#pragma unroll
    for (int kk = 0; kk < 8; ++kk) vv[kk] = f32x4{0.f, 0.f, 0.f, 0.f};
    if ((unsigned)lr < 64u) {
      const float* xp =
          x + (((size_t)(b * 32 + ic0) * 256 + R * 64 + lr) * 256) + Cc * 64 +
          c4 * 4;
#pragma unroll
      for (int kk = 0; kk < 8; ++kk)
        vv[kk] = *reinterpret_cast<const f32x4*>(xp + (size_t)kk * 65536);
    }
  };
  auto stage_write = [&](const f32x4(&vv)[8], int sr) {
#pragma unroll
    for (int j = 0; j < 4; ++j) {
      short8 pk;
#pragma unroll
      for (int kk = 0; kk < 8; ++kk) {
        float e = fmaf(a_r[kk], vv[kk][j], b_r[kk]);
        e = e > 0.f ? e : pa * e;
        pk[kk] = f2bf(e);
      }
      int col = c4 * 4 + j;
      int slot = (s + (col >> 1)) & 3;
      *reinterpret_cast<short8*>(&lds_y[(sr * 64 + col) * 32 + slot * 8]) = pk;
    }
  };

  // ---- 3-deep pipelined staging: rows srb, srb+4, srb+8(tid<128)
  {
    f32x4 va[8], vb[8], vc[8];
    stage_load(va, srb);             // 8 loads in flight
    stage_load(vb, srb + 4);         // 16 loads in flight
    stage_write(va, srb);
    if (tid < 128) stage_load(vc, srb + 8);
    stage_write(vb, srb + 4);
    if (tid < 128) stage_write(vc, srb + 8);
  }
  __syncthreads();

  // ---- weight fragments + bias (post-barrier: lower VGPR during staging)
  bf16x8 wf[18];
#pragma unroll
  for (int th = 0; th < 18; ++th) {
    short8 sv =
        *reinterpret_cast<const short8*>(wfrag + ((size_t)th * 64 + lane) * 8);
    wf[th] = __builtin_bit_cast(bf16x8, sv);
  }
  int l15 = lane & 15, l4 = lane >> 4;
  f32x4 bias0, bias1;
#pragma unroll
  for (int i = 0; i < 4; ++i) {
    bias0[i] = conv_b[l4 * 4 + i];
    bias1[i] = conv_b[16 + l4 * 4 + i];
  }

  // ---- MFMA: each wave does 8 groups of (row r, 16-col block)
  int wv = tid >> 6;
  const short8 z8 = {0, 0, 0, 0, 0, 0, 0, 0};
  for (int g = 0; g < 8; ++g) {
    int gi = wv * 8 + g;
    int r = gi >> 2;
    int c0 = (gi & 3) * 16;
    f32x4 acc0 = bias0, acc1 = bias1;
#pragma unroll
    for (int t9 = 0; t9 < 9; ++t9) {
      const int dy = t9 / 3, dx = t9 - dy * 3;
      int sr = r + dy;
      int col_in = c0 + l15 + dx - 1;     // -1..64 possible at edges
      int colc = col_in & 63;
      int slot = (l4 + (colc >> 1)) & 3;
      short8 sv = *reinterpret_cast<const short8*>(
          &lds_y[(sr * 64 + colc) * 32 + slot * 8]);
      if (dx == 0) {
        if (c0 == 0 && l15 == 0) sv = z8;     // col -1 -> zero pad
      }
      if (dx == 2) {
        if (c0 == 48 && l15 == 15) sv = z8;   // col 64 -> zero pad
      }
      bf16x8 bv = __builtin_bit_cast(bf16x8, sv);
      acc0 = __builtin_amdgcn_mfma_f32_16x16x32_bf16(wf[t9 * 2], bv, acc0, 0, 0, 0);
      acc1 = __builtin_amdgcn_mfma_f32_16x16x32_bf16(wf[t9 * 2 + 1], bv, acc1, 0, 0, 0);
    }
    int grow = R * 64 + h0 + r;
    int gcol = Cc * 64 + c0 + l15;
    float* ob = out + (size_t)b * 2097152 + (size_t)grow * 256 + gcol;
#pragma unroll
    for (int i = 0; i < 4; ++i) {
      ob[(size_t)(l4 * 4 + i) * 65536] = acc0[i];
      ob[(size_t)(16 + l4 * 4 + i) * 65536] = acc1[i];
    }
  }
}

extern "C" void kernel_launch(void* const* d_in, const int* in_sizes, int n_in,
                              void* d_out, int out_size, void* d_ws,
                              size_t ws_size, hipStream_t stream) {
  const float* x = (const float*)d_in[0];
  const float* gamma = (const float*)d_in[1];
  const float* beta = (const float*)d_in[2];
  const float* prelu_a = (const float*)d_in[3];
  const float* conv_w = (const float*)d_in[4];
  const float* conv_b = (const float*)d_in[5];
  float* out = (float*)d_out;

  float* ws = (float*)d_ws;
  float* ws_sum = ws;                          // 16384 floats
  float* ws_sq = ws + 16384;                   // 16384
  unsigned short* wfrag = (unsigned short*)(ws + 32768);   // 18*64*8 shorts

  weights_prep<<<5, 256, 0, stream>>>(conv_w, wfrag);
  stats_partial<<<1024, 256, 0, stream>>>(x, ws_sum, ws_sq);
  conv_mfma<<<4096, 256, 0, stream>>>(x, wfrag, conv_b, prelu_a, ws_sum, ws_sq,
                                      gamma, beta, out);
}